// Round 15
// baseline (112.873 us; speedup 1.0000x reference)
//
#include <hip/hip_runtime.h>

#define HH 3500
#define WW 2500
#define TXs 64
#define TYs 16
#define WIN_H 13                  // per-wave rows: [wy0-4, wy0+8]  (fy in [-4,+4))
#define WIN_W 76                  // cols cx0 .. cx0+75 (19 quads)  (fx in [-4,+4))
#define WIN_W4 19
#define CPLANE (WIN_H*WIN_W4)     // 247 quads per channel per wave
#define NSTG_W (3*CPLANE)         // 741 quads per wave window
#define WWORDS (3*WIN_H*WIN_W)    // 2964 words per wave
#define NTX 40
#define NTY 219
#define NXCD 8

typedef float f32x4 __attribute__((ext_vector_type(4)));
typedef const __attribute__((address_space(1))) float gfloat;
typedef __attribute__((address_space(3))) float lfloat;

__global__ __launch_bounds__(256, 3) void st_warp_v15(
    const float* __restrict__ src,   // [3, H, W]
    const float* __restrict__ flow,  // [2, H, W]
    float* __restrict__ out)         // [3*H*W] warped ++ [H*W*2] norm_grid
{
    __shared__ float smw[4 * WWORDS];       // 47,424 B -> 3 blocks/CU, wave-private segs

    const int nwg = NTX * NTY;              // 8760 (div by 8)
    const int cpx = nwg / NXCD;
    const int bid = blockIdx.x;
    const int sbid = (bid % NXCD) * cpx + bid / NXCD;  // bijective XCD chunking
    const int xt = sbid / NTY;              // column-major tile order
    const int yt = sbid - xt * NTY;

    const int tx0 = xt * TXs;
    const int ty0 = yt * TYs;
    const int cx0 = tx0 - 4;                // mult of 4 -> 16B-aligned staging

    const long HW = (long)HH * WW;
    const int tid  = threadIdx.x;
    const int wave = tid >> 6;
    const int lane = tid & 63;
    const bool colsafe = (cx0 >= 0) && (cx0 + WIN_W <= WW);

    // each wave owns 4 consecutive rows: lanes = 16 x-quads × 4 rows
    const int wy0  = ty0 + wave * 4;        // wave's first output row
    const int ry0w = wy0 - 4;               // wave window top
    const int wxlo = max(cx0, 0);
    const int wxhi = min(cx0 + WIN_W - 1, WW - 1);
    const int wylo = max(ry0w, 0);
    const int wyhi = min(ry0w + WIN_H - 1, HH - 1);

    float* const wseg = smw + wave * WWORDS;  // this wave's private LDS segment

    // ---- per-pixel identity coords ----
    const int r  = lane >> 4;                // 0..3 within wave
    const int xb = tx0 + (lane & 15) * 4;    // 16B-aligned pixel quad
    const int y  = wy0 + r;
    const bool active = (xb < WW) && (y < HH);
    const long idx = (long)y * WW + xb;

    // flow loads issued first (nontemporal: single-use, keep L3 for src)
    f32x4 fx4 = {0,0,0,0}, fy4 = {0,0,0,0};
    if (active) {
        fx4 = __builtin_nontemporal_load(reinterpret_cast<const f32x4*>(flow + idx));
        fy4 = __builtin_nontemporal_load(reinterpret_cast<const f32x4*>(flow + HW + idx));
    }

    // ---- WAVE-LOCAL staging: direct global->LDS DMA into the wave's segment ----
    // dest word = wave_base + 4*(lane + i*64): linear in lane order as required.
    if (colsafe) {
#pragma unroll
        for (int i = 0; i < 12; ++i) {
            const int e = lane + i * 64;
            if (e < NSTG_W) {
                const int c   = e / CPLANE;
                const int rem = e - c * CPLANE;
                const int rr  = rem / WIN_W4;
                const int v   = rem - rr * WIN_W4;
                int gy = ry0w + rr; gy = min(max(gy, 0), HH - 1);
                const float* g = src + (long)c * HW + (long)gy * WW + (cx0 + 4 * v);
                __builtin_amdgcn_global_load_lds(
                    (gfloat*)g, (lfloat*)&wseg[4 * e], 16, 0, 0);
            }
        }
    } else {
        for (int e = lane; e < 3 * WIN_H * WIN_W; e += 64) {
            const int c   = e / (WIN_H * WIN_W);
            const int rem = e - c * (WIN_H * WIN_W);
            const int rr  = rem / WIN_W;
            const int j   = rem - rr * WIN_W;
            int gy = ry0w + rr; gy = min(max(gy, 0), HH - 1);
            int gx = cx0 + j;   gx = min(max(gx, 0), WW - 1);
            wseg[c * (WIN_H * WIN_W) + rr * WIN_W + j] =
                src[(long)c * HW + (long)gy * WW + gx];
        }
    }

    // ---- weights/coords while the DMA flies (pure VALU) ----
    float w00[4], w10[4], w01[4], w11[4];
    float ngv[8];
    int   lb[4];        // word offset of top-left corner within channel plane
    int   p0[4], p1[4]; // true clamped corners for cold path
    int   inwin_mask = 0;

    if (active) {
#pragma unroll
        for (int k = 0; k < 4; ++k) {
            const int x = xb + k;
            const float gx = fx4[k] + (float)x;
            const float gy = fy4[k] + (float)y;

            const float nx = 2.0f * gx / (float)(WW - 1) - 1.0f;
            const float ny = 2.0f * gy / (float)(HH - 1) - 1.0f;
            ngv[2 * k]     = nx;
            ngv[2 * k + 1] = ny;

            // un-normalize exactly as reference (round-trip preserved)
            const float ixp = (nx + 1.0f) * 0.5f * (float)(WW - 1);
            const float iyp = (ny + 1.0f) * 0.5f * (float)(HH - 1);

            const float x0f = floorf(ixp), y0f = floorf(iyp);
            const float wx1 = ixp - x0f, wx0 = 1.0f - wx1;
            const float wy1 = iyp - y0f, wy0 = 1.0f - wy1;

            const int x0 = (int)x0f, y0i = (int)y0f;
            const int x1 = x0 + 1,  y1i = y0i + 1;

            const bool vx0 = (x0  >= 0) & (x0  < WW);
            const bool vx1 = (x1  >= 0) & (x1  < WW);
            const bool vy0 = (y0i >= 0) & (y0i < HH);
            const bool vy1 = (y1i >= 0) & (y1i < HH);

            w00[k] = wx0 * wy0 * ((vx0 & vy0) ? 1.0f : 0.0f);
            w10[k] = wx1 * wy0 * ((vx1 & vy0) ? 1.0f : 0.0f);
            w01[k] = wx0 * wy1 * ((vx0 & vy1) ? 1.0f : 0.0f);
            w11[k] = wx1 * wy1 * ((vx1 & vy1) ? 1.0f : 0.0f);

            const int x0c = min(max(x0,  0), WW - 1);
            const int y0c = min(max(y0i, 0), HH - 1);
            const int x1c = min(max(x1,  0), WW - 1);
            const int y1c = min(max(y1i, 0), HH - 1);
            p0[k] = (y0c << 16) | x0c;
            p1[k] = (y1c << 16) | x1c;

            // hot path: all four corners in-image AND in this wave's window
            const bool inwin = (x0 >= wxlo) & (x1 <= wxhi) &
                               (y0i >= wylo) & (y1i <= wyhi);
            inwin_mask |= (inwin ? 1 : 0) << k;

            lb[k] = (y0i - ry0w) * WIN_W + (x0 - cx0);
        }
    }

    // ---- wave-local wait: only THIS wave's loads must have landed. NO barrier. ----
    asm volatile("s_waitcnt vmcnt(0) lgkmcnt(0)" ::: "memory");

    if (!active) return;

#pragma unroll
    for (int c = 0; c < 3; ++c) {
        const float* __restrict__ buf = wseg + c * (WIN_H * WIN_W);
        float o[4];
#pragma unroll
        for (int k = 0; k < 4; ++k) {
            if ((inwin_mask >> k) & 1) {
                const float* b = buf + lb[k];
                o[k] = b[0] * w00[k] + b[1] * w10[k]
                     + b[WIN_W] * w01[k] + b[WIN_W + 1] * w11[k];
            } else {
                // cold path: true clamped corners with stored weights
                const int x0c = p0[k] & 0xffff, y0c = p0[k] >> 16;
                const int x1c = p1[k] & 0xffff, y1c = p1[k] >> 16;
                const float* __restrict__ s = src + (long)c * HW;
                o[k] = s[(long)y0c * WW + x0c] * w00[k]
                     + s[(long)y0c * WW + x1c] * w10[k]
                     + s[(long)y1c * WW + x0c] * w01[k]
                     + s[(long)y1c * WW + x1c] * w11[k];
            }
        }
        f32x4 v = {o[0], o[1], o[2], o[3]};
        __builtin_nontemporal_store(v, reinterpret_cast<f32x4*>(out + (long)c * HW + idx));
    }
    // norm_grid [H, W, 2] interleaved — NT (never re-read; keep L3 for inputs)
    float* ngbase = out + 3 * HW + 2 * idx;
    f32x4 n0 = {ngv[0], ngv[1], ngv[2], ngv[3]};
    f32x4 n1 = {ngv[4], ngv[5], ngv[6], ngv[7]};
    __builtin_nontemporal_store(n0, reinterpret_cast<f32x4*>(ngbase));
    __builtin_nontemporal_store(n1, reinterpret_cast<f32x4*>(ngbase + 4));
}

extern "C" void kernel_launch(void* const* d_in, const int* in_sizes, int n_in,
                              void* d_out, int out_size, void* d_ws, size_t ws_size,
                              hipStream_t stream) {
    const float* src  = (const float*)d_in[0];
    const float* flow = (const float*)d_in[1];
    float* out = (float*)d_out;
    (void)d_ws; (void)ws_size; (void)in_sizes; (void)n_in; (void)out_size;

    dim3 block(256, 1, 1);
    dim3 grid(NTX * NTY, 1, 1);
    st_warp_v15<<<grid, block, 0, stream>>>(src, flow, out);
}

// Round 16
// 99.307 us; speedup vs baseline: 1.1366x; 1.1366x over previous
//
#include <hip/hip_runtime.h>

#define HH 3500
#define WW 2500
#define TXs 64
#define TYs 32
#define NT_THREADS 512
#define WIN_H 40                  // rows ry0 .. ry0+39, ry0 = ty0-4 (fy in [-4,+4))
#define WIN_W 76                  // cols cx0 .. cx0+75, cx0 = tx0-4 (fx in [-4,+4))
#define WIN_W4 19
#define NSTG (3*WIN_H*WIN_W4)     // 2280 staging quads
#define NTX 40
#define NTY 110                   // ceil(3500/32)
#define NXCD 8

typedef float f32x4 __attribute__((ext_vector_type(4)));

__global__ __launch_bounds__(NT_THREADS, 4) void st_warp_v16(
    const float* __restrict__ src,   // [3, H, W]
    const float* __restrict__ flow,  // [2, H, W]
    float* __restrict__ out)         // [3*H*W] warped ++ [H*W*2] norm_grid
{
    __shared__ float sm[3][WIN_H][WIN_W];   // 36,480 B -> 4 blocks/CU

    const int nwg = NTX * NTY;              // 4400 (div by 8)
    const int cpx = nwg / NXCD;             // 550
    const int bid = blockIdx.x;
    const int sbid = (bid % NXCD) * cpx + bid / NXCD;  // bijective XCD chunking
    const int xt = sbid / NTY;              // column-major tile order
    const int yt = sbid - xt * NTY;

    const int tx0 = xt * TXs;
    const int ty0 = yt * TYs;
    const int cx0 = tx0 - 4;                // mult of 4 -> 16B-aligned staging
    const int ry0 = ty0 - 4;

    const int wxlo = max(cx0, 0);
    const int wxhi = min(cx0 + WIN_W - 1, WW - 1);
    const int wylo = max(ry0, 0);
    const int wyhi = min(ry0 + WIN_H - 1, HH - 1);

    const long HW = (long)HH * WW;
    const int tid = threadIdx.x;
    const bool colsafe = (cx0 >= 0) && (cx0 + WIN_W <= WW);

    // ---- per-pixel identity coords ----
    const int r  = tid >> 4;                 // 0..31
    const int xb = tx0 + (tid & 15) * 4;     // 16B-aligned pixel quad
    const int y  = ty0 + r;
    const bool active = (xb < WW) && (y < HH);  // quads all-in/all-out (WW%4==0)
    const long idx = (long)y * WW + xb;

    // flow loads issued first (cached: L3-resident across replays)
    f32x4 fx4 = {0,0,0,0}, fy4 = {0,0,0,0};
    if (active) {
        fx4 = *reinterpret_cast<const f32x4*>(flow + idx);
        fy4 = *reinterpret_cast<const f32x4*>(flow + HW + idx);
    }

    // ---- monolithic staging: all 3 channels, one barrier total ----
    if (colsafe) {
#pragma unroll
        for (int i = 0; i < 5; ++i) {
            const int e = tid + i * NT_THREADS;
            if (e < NSTG) {
                const int c   = e / (WIN_H * WIN_W4);
                const int rem = e - c * (WIN_H * WIN_W4);
                const int rr  = rem / WIN_W4;
                const int v   = rem - rr * WIN_W4;
                int gy = ry0 + rr; gy = min(max(gy, 0), HH - 1);
                const f32x4 val = *reinterpret_cast<const f32x4*>(
                    src + (long)c * HW + (long)gy * WW + (cx0 + 4 * v));
                *reinterpret_cast<f32x4*>(&sm[c][rr][4 * v]) = val;
            }
        }
    } else {
        for (int e = tid; e < 3 * WIN_H * WIN_W; e += NT_THREADS) {
            const int c   = e / (WIN_H * WIN_W);
            const int rem = e - c * (WIN_H * WIN_W);
            const int rr  = rem / WIN_W;
            const int j   = rem - rr * WIN_W;
            int gy = ry0 + rr; gy = min(max(gy, 0), HH - 1);
            int gx = cx0 + j;  gx = min(max(gx, 0), WW - 1);
            sm[c][rr][j] = src[(long)c * HW + (long)gy * WW + gx];
        }
    }

    // ---- weights/coords BEFORE the barrier (pure VALU, overlaps staging) ----
    float w00[4], w10[4], w01[4], w11[4];
    float ngv[8];
    int   lb[4];        // LDS word offset of top-left corner (hot path)
    int   p0[4];        // packed (y0c<<16)|x0c  — true clamped corner 0
    int   p1[4];        // packed (y1c<<16)|x1c  — true clamped corner 1
    int   inwin_mask = 0;

    if (active) {
#pragma unroll
        for (int k = 0; k < 4; ++k) {
            const int x = xb + k;
            const float gx = fx4[k] + (float)x;
            const float gy = fy4[k] + (float)y;

            const float nx = 2.0f * gx / (float)(WW - 1) - 1.0f;
            const float ny = 2.0f * gy / (float)(HH - 1) - 1.0f;
            ngv[2 * k]     = nx;
            ngv[2 * k + 1] = ny;

            // un-normalize exactly as reference (round-trip preserved)
            const float ixp = (nx + 1.0f) * 0.5f * (float)(WW - 1);
            const float iyp = (ny + 1.0f) * 0.5f * (float)(HH - 1);

            const float x0f = floorf(ixp), y0f = floorf(iyp);
            const float wx1 = ixp - x0f, wx0 = 1.0f - wx1;
            const float wy1 = iyp - y0f, wy0 = 1.0f - wy1;

            const int x0 = (int)x0f, y0i = (int)y0f;
            const int x1 = x0 + 1,  y1i = y0i + 1;

            const bool vx0 = (x0  >= 0) & (x0  < WW);
            const bool vx1 = (x1  >= 0) & (x1  < WW);
            const bool vy0 = (y0i >= 0) & (y0i < HH);
            const bool vy1 = (y1i >= 0) & (y1i < HH);

            w00[k] = wx0 * wy0 * ((vx0 & vy0) ? 1.0f : 0.0f);
            w10[k] = wx1 * wy0 * ((vx1 & vy0) ? 1.0f : 0.0f);
            w01[k] = wx0 * wy1 * ((vx0 & vy1) ? 1.0f : 0.0f);
            w11[k] = wx1 * wy1 * ((vx1 & vy1) ? 1.0f : 0.0f);

            const int x0c = min(max(x0,  0), WW - 1);
            const int y0c = min(max(y0i, 0), HH - 1);
            const int x1c = min(max(x1,  0), WW - 1);
            const int y1c = min(max(y1i, 0), HH - 1);
            p0[k] = (y0c << 16) | x0c;
            p1[k] = (y1c << 16) | x1c;

            // hot path: ALL FOUR corners in-image AND in-window -> no clamping
            const bool inwin = (x0 >= wxlo) & (x1 <= wxhi) &
                               (y0i >= wylo) & (y1i <= wyhi);
            inwin_mask |= (inwin ? 1 : 0) << k;

            lb[k] = (y0i - ry0) * WIN_W + (x0 - cx0);
        }
    }

    __syncthreads();   // the ONLY barrier

    if (!active) return;

#pragma unroll
    for (int c = 0; c < 3; ++c) {
        const float* __restrict__ buf = &sm[c][0][0];
        float o[4];
#pragma unroll
        for (int k = 0; k < 4; ++k) {
            if ((inwin_mask >> k) & 1) {
                const float* b = buf + lb[k];
                o[k] = b[0] * w00[k] + b[1] * w10[k]
                     + b[WIN_W] * w01[k] + b[WIN_W + 1] * w11[k];
            } else {
                // cold path: true clamped corners with stored weights
                const int x0c = p0[k] & 0xffff, y0c = p0[k] >> 16;
                const int x1c = p1[k] & 0xffff, y1c = p1[k] >> 16;
                const float* __restrict__ s = src + (long)c * HW;
                o[k] = s[(long)y0c * WW + x0c] * w00[k]
                     + s[(long)y0c * WW + x1c] * w10[k]
                     + s[(long)y1c * WW + x0c] * w01[k]
                     + s[(long)y1c * WW + x1c] * w11[k];
            }
        }
        f32x4 v = {o[0], o[1], o[2], o[3]};
        __builtin_nontemporal_store(v, reinterpret_cast<f32x4*>(out + (long)c * HW + idx));
    }
    // norm_grid [H, W, 2] interleaved — NT (never re-read; keep L3 for inputs)
    float* ngbase = out + 3 * HW + 2 * idx;
    f32x4 n0 = {ngv[0], ngv[1], ngv[2], ngv[3]};
    f32x4 n1 = {ngv[4], ngv[5], ngv[6], ngv[7]};
    __builtin_nontemporal_store(n0, reinterpret_cast<f32x4*>(ngbase));
    __builtin_nontemporal_store(n1, reinterpret_cast<f32x4*>(ngbase + 4));
}

extern "C" void kernel_launch(void* const* d_in, const int* in_sizes, int n_in,
                              void* d_out, int out_size, void* d_ws, size_t ws_size,
                              hipStream_t stream) {
    const float* src  = (const float*)d_in[0];
    const float* flow = (const float*)d_in[1];
    float* out = (float*)d_out;
    (void)d_ws; (void)ws_size; (void)in_sizes; (void)n_in; (void)out_size;

    dim3 block(NT_THREADS, 1, 1);
    dim3 grid(NTX * NTY, 1, 1);
    st_warp_v16<<<grid, block, 0, stream>>>(src, flow, out);
}